// Round 1
// baseline (411.196 us; speedup 1.0000x reference)
//
#include <hip/hip_runtime.h>

typedef _Float16 half8 __attribute__((ext_vector_type(8)));
typedef __attribute__((ext_vector_type(4))) float f32x4;

#define C_DIM 512
#define S_DIM 4096
#define NCOL 165      // 3 * sum(k=1..10)
#define NCOLP 176     // padded to 11 * 16
#define M_OUT 64
#define ROWS 80       // 16-row-aligned GEMM rows (5 m-frags)
#define DROWS 73      // rows actually DMA'd from x: s0-9 .. s0+63 (rest = zeros)
#define BK 32
#define NCHUNK 16     // 512 / 32
#define RJ 9          // float4 slots per LDS row: 8 data + 1 pad (36-word stride, ~2-way free)
#define BUFSZ 12288   // bytes per A buffer: 768 slots * 16B = 12 DMA instr * 1KB
#define NBUF 4        // A buffers; DMA issued 3 chunks ahead
#define YST 180       // epilogue Y row stride (words)
#define YSLOT 2880    // 16 * YST

struct WP { const float* w[10]; };

// Pack weights into B^T fp16: bt[col][c]; last block zeroes the 4KB halo zero-buffer.
__global__ __launch_bounds__(256) void prep_kernel(WP wp, _Float16* bt, float4* zbuf) {
  if (blockIdx.x == NCOLP * C_DIM / 256) {
    zbuf[threadIdx.x] = make_float4(0.f, 0.f, 0.f, 0.f);   // 256*16B = 4KB zeros
    return;
  }
  int idx = blockIdx.x * 256 + threadIdx.x;   // 176*512 threads exactly
  int col = idx >> 9;
  int c = idx & 511;
  float v = 0.f;
  if (col < NCOL) {
    int kw = 1, base = 0;
    while (col >= base + 3 * kw) { base += 3 * kw; ++kw; }
    int rem = col - base;
    int t = rem / 3, p = rem - 3 * t;
    v = wp.w[kw - 1][(t * C_DIM + c) * 3 + p];   // w_k layout (k, C, P)
  }
  bt[col * C_DIM + c] = (_Float16)v;            // RNE
}

__device__ __forceinline__ void gld16(const void* g, void* l) {
  __builtin_amdgcn_global_load_lds(
      (const __attribute__((address_space(1))) unsigned int*)(const unsigned int*)g,
      (__attribute__((address_space(3))) unsigned int*)(unsigned int*)l, 16, 0, 0);
}

template <int N>
__device__ __forceinline__ void wait_vm() {
  __asm__ volatile("s_waitcnt vmcnt(%0)" ::"i"(N) : "memory");
}
// LDS-visibility barrier: does NOT drain vmcnt (DMA/global loads stay in flight).
__device__ __forceinline__ void barrier_lgkm() {
  __asm__ volatile("s_waitcnt lgkmcnt(0)\n\ts_barrier" ::: "memory");
}

__global__ __launch_bounds__(256, 3) void conv_kernel(const float* __restrict__ x,
                                                      const _Float16* __restrict__ bt,
                                                      const float* __restrict__ zbuf,
                                                      float* __restrict__ out) {
  // LDS: 4 A-buffers (fp32, DMA-filled 3-ahead, 12KB each) = 49152 B.
  // Epilogue overlays [0, 23040) as 2 slots of 16 x YST fp32.
  __shared__ __align__(16) unsigned char smem[NBUF * BUFSZ];
  float* Ys = (float*)smem;

  const int tid = threadIdx.x;
  // XCD-bijective swizzle: grid = 2048 = 8 XCDs * 256. Consecutive tiles land on
  // the SAME XCD so the 9 halo rows hit that XCD's L2 instead of LLC/HBM.
  const int wg = blockIdx.x;
  const int lin = (wg & 7) * 256 + (wg >> 3);
  const int b = lin >> 6;               // 64 tiles per batch
  const int tile = lin & 63;
  const int s0 = tile * M_OUT;
  const int sBase = s0 - 9;             // halo start (9 = K-1 causal taps)
  const int wave = tid >> 6;
  const int lane = tid & 63;
  const int l15 = lane & 15;
  const int quad = lane >> 4;
  const int wnu = __builtin_amdgcn_readfirstlane(wave);
  const int n0 = wave * 3;              // n-tile split 3/3/3/2
  const int nmine = (wave < 3) ? 3 : 2;

  // --- per-wave B fragment pointers (global, L1/L2-resident) ---
  const half8* bptr[3];
#pragma unroll
  for (int nn = 0; nn < 3; ++nn) {
    int cr = (n0 + nn) * 16 + l15;
    bptr[nn] = (const half8*)&bt[(nn < nmine ? cr : l15) * C_DIM + quad * 8];
  }

  // --- per-lane DMA source addresses (3 instructions per wave per chunk) ---
  // Rows 0..72 come from x (s = s0-9 .. s0+63); rows 73..79 + j==8 pad slots DMA
  // zeros from zbuf (L2-resident) so GEMM rows 73..79 are deterministic zeros.
  const char* asrc[3];
#pragma unroll
  for (int i = 0; i < 3; ++i) {
    int t = wave * 3 + i;               // 0..11
    int sigma = t * 64 + lane;          // 0..767
    int row = sigma / RJ;
    int j = sigma - row * RJ;
    int s = sBase + row;
    bool ok = (j < 8) && (row < DROWS) && (s >= 0);
    asrc[i] = ok ? (const char*)&x[((size_t)(b * S_DIM + s)) * C_DIM + j * 4]
                 : (const char*)zbuf + lane * 16;  // zeros; +ch*128 stays <4KB
  }
  const int ldst = wnu * 3;             // wave's DMA slot base (wave-uniform)

  f32x4 acc[5][3];
#pragma unroll
  for (int m = 0; m < 5; ++m)
#pragma unroll
    for (int n = 0; n < 3; ++n) acc[m][n] = (f32x4){0.f, 0.f, 0.f, 0.f};

  // ---------- prologue ----------
  // Issue order (oldest->newest): B0, B1, D0, D1, D2. Wait for D0 -> vmcnt(6):
  // drains B0,B1,D0; keeps D1,D2 in flight.
  half8 breg[3][3];                     // ring: slot ch%3 holds B(ch)
#pragma unroll
  for (int nn = 0; nn < 3; ++nn)
    if (nn < nmine) breg[0][nn] = bptr[nn][0];
#pragma unroll
  for (int nn = 0; nn < 3; ++nn)
    if (nn < nmine) breg[1][nn] = bptr[nn][4];
#pragma unroll
  for (int c = 0; c < 3; ++c)
#pragma unroll
    for (int i = 0; i < 3; ++i)
      gld16(asrc[i] + c * 128, smem + c * BUFSZ + (ldst + i) * 1024);
  wait_vm<6>();
  barrier_lgkm();

#pragma unroll
  for (int ch = 0; ch < NCHUNK; ++ch) {
    // B(ch+2) into ring slot (ch+2)%3 — issued BEFORE this chunk's DMA so that
    // MFMA(ch)'s implicit wait for B(ch) (issued 2 chunks ago) drains nothing newer.
    if (ch + 2 < NCHUNK) {
#pragma unroll
      for (int nn = 0; nn < 3; ++nn)
        if (nn < nmine) breg[(ch + 2) % 3][nn] = bptr[nn][(ch + 2) * 4];
    }
    // DMA(ch+3): lands 3 chunks from now; never force-drained early.
    if (ch + 3 < NCHUNK) {
#pragma unroll
      for (int i = 0; i < 3; ++i)
        gld16(asrc[i] + (ch + 3) * 128, smem + ((ch + 3) % NBUF) * BUFSZ + (ldst + i) * 1024);
    }
    // compute on buf ch%NBUF: fp32 frags -> fp16 RNE -> MFMA
    const float* Af = (const float*)(smem + (ch % NBUF) * BUFSZ);
#pragma unroll
    for (int m = 0; m < 5; ++m) {
      const float* rp = Af + (m * 16 + l15) * (RJ * 4) + quad * 8;
      f32x4 a0 = *(const f32x4*)rp;
      f32x4 a1 = *(const f32x4*)(rp + 4);
      half8 ah = {(_Float16)a0[0], (_Float16)a0[1], (_Float16)a0[2], (_Float16)a0[3],
                  (_Float16)a1[0], (_Float16)a1[1], (_Float16)a1[2], (_Float16)a1[3]};
#pragma unroll
      for (int nn = 0; nn < 3; ++nn)
        if (nn < nmine)
          acc[m][nn] =
              __builtin_amdgcn_mfma_f32_16x16x32_f16(ah, breg[ch % 3][nn], acc[m][nn], 0, 0, 0);
    }
    // End-of-chunk: drain exactly DMA(ch+1); keep {B(ch+1),D(ch+2),B(ch+2),D(ch+3)}.
    if (ch == 0) wait_vm<9>();
    else if (ch <= 12) wait_vm<12>();
    else if (ch == 13) wait_vm<9>();
    else if (ch == 14) wait_vm<3>();
    if (ch < NCHUNK - 1) barrier_lgkm();
  }

  __syncthreads();                      // full drain before overlaying A bufs with Ys

  // ---- epilogue: d-sum + relu via LDS, ping-pong 16 x YST fp32 slots ----
  // C/D layout: col = lane&15 (global col = (n0+nn)*16 + l15), row = quad*4 + reg.
  // A-window shift: output s = s0+16(i-1)+r sits at LDS row 16(i-1)+9+r, so the
  // needed Y rows [16(i-1), 16(i-1)+24] live in acc[i-1] (prev slot) and acc[i]
  // (cur slot): rr = r-d+9; rr<16 -> prev slot row rr, rr>=16 -> cur slot row rr-16.
#pragma unroll
  for (int i = 1; i <= 4; ++i) {
    if (i == 1) {
#pragma unroll
      for (int nn = 0; nn < 3; ++nn)
        if (nn < nmine)
#pragma unroll
          for (int r = 0; r < 4; ++r)
            Ys[0 * YSLOT + (quad * 4 + r) * YST + (n0 + nn) * 16 + l15] = acc[0][nn][r];
    }
#pragma unroll
    for (int nn = 0; nn < 3; ++nn)
      if (nn < nmine)
#pragma unroll
        for (int r = 0; r < 4; ++r)
          Ys[(i & 1) * YSLOT + (quad * 4 + r) * YST + (n0 + nn) * 16 + l15] = acc[i][nn][r];
    __syncthreads();
    for (int o = tid; o < 480; o += 256) {
      int r = o / 30;
      int j = o - 30 * r;
      int kw = j / 3 + 1;
      int p = j - (kw - 1) * 3;
      int base = 3 * (kw * (kw - 1)) / 2;
      float sum = 0.f;
      for (int d = 0; d < kw; ++d) {
        int rr = r - d + 9;
        int slot = (rr >= 16) ? (i & 1) : ((i ^ 1) & 1);
        int lr = (rr >= 16) ? (rr - 16) : rr;
        int colv = base + (kw - 1 - d) * 3 + p;
        sum += Ys[slot * YSLOT + lr * YST + colv];
      }
      int s = s0 + 16 * (i - 1) + r;
      out[((size_t)(b * S_DIM + s)) * 30 + j] = fmaxf(sum, 0.f);
    }
    __syncthreads();
  }
}

extern "C" void kernel_launch(void* const* d_in, const int* in_sizes, int n_in,
                              void* d_out, int out_size, void* d_ws, size_t ws_size,
                              hipStream_t stream) {
  const float* x = (const float*)d_in[0];
  WP wp;
  for (int k = 0; k < 10; ++k) wp.w[k] = (const float*)d_in[k + 1];
  _Float16* bt = (_Float16*)d_ws;                                // 180224 B
  float4* zbuf = (float4*)((char*)d_ws + NCOLP * C_DIM * 2);     // 4 KB zeros
  prep_kernel<<<NCOLP * C_DIM / 256 + 1, 256, 0, stream>>>(wp, bt, zbuf);
  conv_kernel<<<32 * (S_DIM / M_OUT), 256, 0, stream>>>(x, bt, (const float*)zbuf,
                                                        (float*)d_out);
}

// Round 2
// 398.927 us; speedup vs baseline: 1.0308x; 1.0308x over previous
//
#include <hip/hip_runtime.h>

typedef _Float16 half8 __attribute__((ext_vector_type(8)));
typedef __attribute__((ext_vector_type(4))) float f32x4;

#define C_DIM 512
#define S_DIM 4096
#define NCOL 165      // 3 * sum(k=1..10)
#define NCOLP 176     // padded to 11 * 16
#define M_OUT 64
#define ROWS 80       // 16-row-aligned GEMM rows (5 m-frags)
#define DROWS 73      // rows actually DMA'd from x: s0-9 .. s0+63 (rest = zeros)
#define BK 32
#define NCHUNK 16     // 512 / 32
#define RJ 9          // float4 slots per LDS row: 8 data + 1 pad (36-word stride, ~2-way free)
#define BUFSZ 12288   // bytes per A buffer: 768 slots * 16B = 12 DMA instr * 1KB
#define NBUF 4        // A buffers; DMA issued 3 chunks ahead
#define YST 180       // epilogue Y row stride (words)
#define YSLOT 2880    // 16 * YST

struct WP { const float* w[10]; };

// Pack weights into B^T fp16: bt[col][c]; last block zeroes the 4KB halo zero-buffer.
__global__ __launch_bounds__(256) void prep_kernel(WP wp, _Float16* bt, float4* zbuf) {
  if (blockIdx.x == NCOLP * C_DIM / 256) {
    zbuf[threadIdx.x] = make_float4(0.f, 0.f, 0.f, 0.f);   // 256*16B = 4KB zeros
    return;
  }
  int idx = blockIdx.x * 256 + threadIdx.x;   // 176*512 threads exactly
  int col = idx >> 9;
  int c = idx & 511;
  float v = 0.f;
  if (col < NCOL) {
    int kw = 1, base = 0;
    while (col >= base + 3 * kw) { base += 3 * kw; ++kw; }
    int rem = col - base;
    int t = rem / 3, p = rem - 3 * t;
    v = wp.w[kw - 1][(t * C_DIM + c) * 3 + p];   // w_k layout (k, C, P)
  }
  bt[col * C_DIM + c] = (_Float16)v;            // RNE
}

__device__ __forceinline__ void gld16(const void* g, void* l) {
  __builtin_amdgcn_global_load_lds(
      (const __attribute__((address_space(1))) unsigned int*)(const unsigned int*)g,
      (__attribute__((address_space(3))) unsigned int*)(unsigned int*)l, 16, 0, 0);
}

template <int N>
__device__ __forceinline__ void wait_vm() {
  __asm__ volatile("s_waitcnt vmcnt(%0)" ::"i"(N) : "memory");
}
// LDS-visibility barrier: does NOT drain vmcnt (DMA/global loads stay in flight).
__device__ __forceinline__ void barrier_lgkm() {
  __asm__ volatile("s_waitcnt lgkmcnt(0)\n\ts_barrier" ::: "memory");
}

__global__ __launch_bounds__(256, 3) void conv_kernel(const float* __restrict__ x,
                                                      const _Float16* __restrict__ bt,
                                                      const float* __restrict__ zbuf,
                                                      float* __restrict__ out) {
  // LDS: 4 A-buffers (fp32, DMA-filled 3-ahead, 12KB each) = 49152 B.
  // Epilogue overlays [0, 23040) as 2 slots of 16 x YST fp32.
  __shared__ __align__(16) unsigned char smem[NBUF * BUFSZ];
  float* Ys = (float*)smem;

  const int tid = threadIdx.x;
  // No XCD swizzle: R1 A/B showed it regresses this streaming workload (~2-3%);
  // halo reuse is only 9/73 of A fetch, so dispatch-order locality wins.
  const int b = blockIdx.x >> 6;        // 64 tiles per batch
  const int tile = blockIdx.x & 63;
  const int s0 = tile * M_OUT;
  const int sBase = s0 - 9;             // halo start (9 = K-1 causal taps)
  const int wave = tid >> 6;
  const int lane = tid & 63;
  const int l15 = lane & 15;
  const int quad = lane >> 4;
  const int wnu = __builtin_amdgcn_readfirstlane(wave);
  const int n0 = wave * 3;              // n-tile split 3/3/3/2
  const int nmine = (wave < 3) ? 3 : 2;

  // --- per-wave B fragment pointers (global, L1/L2-resident) ---
  const half8* bptr[3];
#pragma unroll
  for (int nn = 0; nn < 3; ++nn) {
    int cr = (n0 + nn) * 16 + l15;
    bptr[nn] = (const half8*)&bt[(nn < nmine ? cr : l15) * C_DIM + quad * 8];
  }

  // --- per-lane DMA source addresses (3 instructions per wave per chunk) ---
  // Rows 0..72 come from x (s = s0-9 .. s0+63); rows 73..79 + j==8 pad slots DMA
  // zeros from zbuf (L2-resident) so GEMM rows 73..79 are deterministic zeros.
  const char* asrc[3];
#pragma unroll
  for (int i = 0; i < 3; ++i) {
    int t = wave * 3 + i;               // 0..11
    int sigma = t * 64 + lane;          // 0..767
    int row = sigma / RJ;
    int j = sigma - row * RJ;
    int s = sBase + row;
    bool ok = (j < 8) && (row < DROWS) && (s >= 0);
    asrc[i] = ok ? (const char*)&x[((size_t)(b * S_DIM + s)) * C_DIM + j * 4]
                 : (const char*)zbuf + lane * 16;  // zeros; +ch*128 stays <4KB
  }
  const int ldst = wnu * 3;             // wave's DMA slot base (wave-uniform)

  f32x4 acc[5][3];
#pragma unroll
  for (int m = 0; m < 5; ++m)
#pragma unroll
    for (int n = 0; n < 3; ++n) acc[m][n] = (f32x4){0.f, 0.f, 0.f, 0.f};

  // ---------- prologue ----------
  // Issue order (oldest->newest): B0, B1, D0, D1, D2. Wait for D0 -> vmcnt(6):
  // drains B0,B1,D0; keeps D1,D2 in flight.
  half8 breg[3][3];                     // ring: slot ch%3 holds B(ch)
#pragma unroll
  for (int nn = 0; nn < 3; ++nn)
    if (nn < nmine) breg[0][nn] = bptr[nn][0];
#pragma unroll
  for (int nn = 0; nn < 3; ++nn)
    if (nn < nmine) breg[1][nn] = bptr[nn][4];
#pragma unroll
  for (int c = 0; c < 3; ++c)
#pragma unroll
    for (int i = 0; i < 3; ++i)
      gld16(asrc[i] + c * 128, smem + c * BUFSZ + (ldst + i) * 1024);
  wait_vm<6>();
  barrier_lgkm();

#pragma unroll
  for (int ch = 0; ch < NCHUNK; ++ch) {
    // B(ch+2) into ring slot (ch+2)%3 — issued BEFORE this chunk's DMA so that
    // MFMA(ch)'s implicit wait for B(ch) (issued 2 chunks ago) drains nothing newer.
    if (ch + 2 < NCHUNK) {
#pragma unroll
      for (int nn = 0; nn < 3; ++nn)
        if (nn < nmine) breg[(ch + 2) % 3][nn] = bptr[nn][(ch + 2) * 4];
    }
    // DMA(ch+3): lands 3 chunks from now; never force-drained early.
    if (ch + 3 < NCHUNK) {
#pragma unroll
      for (int i = 0; i < 3; ++i)
        gld16(asrc[i] + (ch + 3) * 128, smem + ((ch + 3) % NBUF) * BUFSZ + (ldst + i) * 1024);
    }
    // compute on buf ch%NBUF: fp32 frags -> fp16 RNE -> MFMA
    const float* Af = (const float*)(smem + (ch % NBUF) * BUFSZ);
#pragma unroll
    for (int m = 0; m < 5; ++m) {
      const float* rp = Af + (m * 16 + l15) * (RJ * 4) + quad * 8;
      f32x4 a0 = *(const f32x4*)rp;
      f32x4 a1 = *(const f32x4*)(rp + 4);
      half8 ah = {(_Float16)a0[0], (_Float16)a0[1], (_Float16)a0[2], (_Float16)a0[3],
                  (_Float16)a1[0], (_Float16)a1[1], (_Float16)a1[2], (_Float16)a1[3]};
#pragma unroll
      for (int nn = 0; nn < 3; ++nn)
        if (nn < nmine)
          acc[m][nn] =
              __builtin_amdgcn_mfma_f32_16x16x32_f16(ah, breg[ch % 3][nn], acc[m][nn], 0, 0, 0);
    }
    // End-of-chunk: drain exactly DMA(ch+1); keep {B(ch+1),D(ch+2),B(ch+2),D(ch+3)}.
    if (ch == 0) wait_vm<9>();
    else if (ch <= 12) wait_vm<12>();
    else if (ch == 13) wait_vm<9>();
    else if (ch == 14) wait_vm<3>();
    if (ch < NCHUNK - 1) barrier_lgkm();
  }

  __syncthreads();                      // full drain before overlaying A bufs with Ys

  // ---- epilogue: d-sum + relu via LDS, ping-pong 16 x YST fp32 slots ----
  // C/D layout: col = lane&15 (global col = (n0+nn)*16 + l15), row = quad*4 + reg.
  // A-window shift: output s = s0+16(i-1)+r sits at LDS row 16(i-1)+9+r, so the
  // needed Y rows [16(i-1), 16(i-1)+24] live in acc[i-1] (prev slot) and acc[i]
  // (cur slot): rr = r-d+9; rr<16 -> prev slot row rr, rr>=16 -> cur slot row rr-16.
#pragma unroll
  for (int i = 1; i <= 4; ++i) {
    if (i == 1) {
#pragma unroll
      for (int nn = 0; nn < 3; ++nn)
        if (nn < nmine)
#pragma unroll
          for (int r = 0; r < 4; ++r)
            Ys[0 * YSLOT + (quad * 4 + r) * YST + (n0 + nn) * 16 + l15] = acc[0][nn][r];
    }
#pragma unroll
    for (int nn = 0; nn < 3; ++nn)
      if (nn < nmine)
#pragma unroll
        for (int r = 0; r < 4; ++r)
          Ys[(i & 1) * YSLOT + (quad * 4 + r) * YST + (n0 + nn) * 16 + l15] = acc[i][nn][r];
    __syncthreads();
    for (int o = tid; o < 480; o += 256) {
      int r = o / 30;
      int j = o - 30 * r;
      int kw = j / 3 + 1;
      int p = j - (kw - 1) * 3;
      int base = 3 * (kw * (kw - 1)) / 2;
      float sum = 0.f;
      for (int d = 0; d < kw; ++d) {
        int rr = r - d + 9;
        int slot = (rr >= 16) ? (i & 1) : ((i ^ 1) & 1);
        int lr = (rr >= 16) ? (rr - 16) : rr;
        int colv = base + (kw - 1 - d) * 3 + p;
        sum += Ys[slot * YSLOT + lr * YST + colv];
      }
      int s = s0 + 16 * (i - 1) + r;
      out[((size_t)(b * S_DIM + s)) * 30 + j] = fmaxf(sum, 0.f);
    }
    __syncthreads();
  }
}

extern "C" void kernel_launch(void* const* d_in, const int* in_sizes, int n_in,
                              void* d_out, int out_size, void* d_ws, size_t ws_size,
                              hipStream_t stream) {
  const float* x = (const float*)d_in[0];
  WP wp;
  for (int k = 0; k < 10; ++k) wp.w[k] = (const float*)d_in[k + 1];
  _Float16* bt = (_Float16*)d_ws;                                // 180224 B
  float4* zbuf = (float4*)((char*)d_ws + NCOLP * C_DIM * 2);     // 4 KB zeros
  prep_kernel<<<NCOLP * C_DIM / 256 + 1, 256, 0, stream>>>(wp, bt, zbuf);
  conv_kernel<<<32 * (S_DIM / M_OUT), 256, 0, stream>>>(x, bt, (const float*)zbuf,
                                                        (float*)d_out);
}